// Round 4
// baseline (298.664 us; speedup 1.0000x reference)
//
#include <hip/hip_runtime.h>
#include <cmath>

typedef __attribute__((ext_vector_type(8))) short s16x8;   // 8 bf16 = 4 VGPRs (MFMA A/B frag)
typedef __attribute__((ext_vector_type(4))) short s16x4;
typedef __attribute__((ext_vector_type(4))) float f32x4;   // MFMA C/D frag

__device__ __forceinline__ short f2bf(float f) {
    union { float f; unsigned u; } v; v.f = f;
    unsigned r = v.u + 0x7FFFu + ((v.u >> 16) & 1u);   // RNE
    return (short)(r >> 16);
}
__device__ __forceinline__ float bf2f(short s) {
    union { unsigned u; float f; } v; v.u = ((unsigned)(unsigned short)s) << 16;
    return v.f;
}

// ---- ws layout ----
// shorts: [emb_bf16 6,400,064][w1seqT 4096][w1topT 4096][w2T 2048]  = 12,820,608 B
// floats: [qc 8192*64][scores 8192*200]                             -> total 21,471,360 B
#define EMB_ELEMS 6400064
#define W1SEQ_SH  6400064
#define W1TOP_SH  6404160
#define W2_SH     6408256
#define QC_F      3205152
#define SC_F      (QC_F + 8192 * 64)

// ============================ K1: prep ============================
__global__ __launch_bounds__(256)
void din_prep_kernel(const float* __restrict__ emb,
                     const float* __restrict__ aw1,
                     const float* __restrict__ aw2,
                     short* __restrict__ ws)
{
    if (blockIdx.x < 6251) {
        long e4 = ((long)blockIdx.x * 256 + threadIdx.x) * 4;
        if (e4 < EMB_ELEMS) {
            float4 v = *(const float4*)(emb + e4);
            s16x4 bv = { f2bf(v.x), f2bf(v.y), f2bf(v.z), f2bf(v.w) };
            *(s16x4*)(ws + e4) = bv;
        }
    } else {
        const int t = threadIdx.x;
        for (int idx = t; idx < 4096; idx += 256) {       // w1seqT[n][k] = aw1[64+k][n]
            int k = idx >> 6, n = idx & 63;
            ws[W1SEQ_SH + n * 64 + k] = f2bf(aw1[(64 + k) * 64 + n]);
        }
        for (int idx = t; idx < 4096; idx += 256) {       // w1topT[n][k] = aw1[k][n]
            int k = idx >> 6, n = idx & 63;
            ws[W1TOP_SH + n * 64 + k] = f2bf(aw1[k * 64 + n]);
        }
        for (int idx = t; idx < 2048; idx += 256) {       // w2T[n][k] = aw2[k][n]
            int k = idx >> 5, n = idx & 31;
            ws[W2_SH + n * 64 + k] = f2bf(aw2[k * 32 + n]);
        }
    }
}

// ============================ K2: qc = tgt_emb @ aw1_top + ab1 ============================
// one wave per 16 batch rows; grid 128 blocks x 4 waves x 16 = 8192
__global__ __launch_bounds__(256)
void din_qc_kernel(const int* __restrict__ tgt_item,
                   const float* __restrict__ ab1,
                   short* __restrict__ ws)
{
    const int t = threadIdx.x, lane = t & 63, wave = t >> 6;
    const int quad = lane >> 4, r16 = lane & 15;
    const short* embbf = ws;
    const short* w1t   = ws + W1TOP_SH;
    float* qc = (float*)ws + QC_F;

    const int b0 = (blockIdx.x * 4 + wave) * 16;
    const int it = tgt_item[b0 + r16];
    const short* rp = embbf + it * 64 + quad * 8;
    s16x8 a0 = *(const s16x8*)(rp);
    s16x8 a1 = *(const s16x8*)(rp + 32);

    f32x4 acc[4] = {{0,0,0,0},{0,0,0,0},{0,0,0,0},{0,0,0,0}};
    #pragma unroll
    for (int nt = 0; nt < 4; ++nt) {
        s16x8 b_0 = *(const s16x8*)(w1t + (nt * 16 + r16) * 64 + quad * 8);
        s16x8 b_1 = *(const s16x8*)(w1t + (nt * 16 + r16) * 64 + 32 + quad * 8);
        acc[nt] = __builtin_amdgcn_mfma_f32_16x16x32_bf16(a0, b_0, acc[nt], 0, 0, 0);
        acc[nt] = __builtin_amdgcn_mfma_f32_16x16x32_bf16(a1, b_1, acc[nt], 0, 0, 0);
    }
    #pragma unroll
    for (int nt = 0; nt < 4; ++nt) {
        float bias = ab1[nt * 16 + r16];
        #pragma unroll
        for (int rr = 0; rr < 4; ++rr)   // D: row=quad*4+rr, col=nt*16+r16
            qc[(b0 + quad * 4 + rr) * 64 + nt * 16 + r16] = acc[nt][rr] + bias;
    }
}

// ============================ K3: attention scores ============================
// one wave per 16-row chunk; flat grid over (b, chunk); no __syncthreads
#define H1_PITCH 72
__global__ __launch_bounds__(256, 4)
void din_att_kernel(const int* __restrict__ item_seq,
                    const int* __restrict__ seq_len_p,
                    const float* __restrict__ ab2,
                    const float* __restrict__ aw3, const float* __restrict__ ab3,
                    short* __restrict__ ws)
{
    const int t = threadIdx.x, lane = t & 63, wave = t >> 6;
    const int quad = lane >> 4, r16 = lane & 15;
    __shared__ short s_h1[4 * 16 * H1_PITCH];

    const unsigned s = blockIdx.x * 4 + wave;      // 0 .. 106495
    const int b = s / 13u;
    const int c = s - b * 13u;
    const int len = seq_len_p[b];
    const int row0 = c * 16;
    if (row0 >= len) return;                        // wave-uniform early exit

    const short* embbf = ws;
    const short* w1f   = ws + W1SEQ_SH;
    const short* w2f   = ws + W2_SH;
    const float* qc    = (const float*)ws + QC_F + b * 64;
    float* scores      = (float*)ws + SC_F + b * 200;

    int r = row0 + r16; if (r > 199) r = 199;
    const int it = item_seq[b * 200 + r];
    const short* rp = embbf + it * 64 + quad * 8;
    s16x8 a0 = *(const s16x8*)(rp);
    s16x8 a1 = *(const s16x8*)(rp + 32);

    // H1 = relu(seq @ w1seq + qc):  16x64, K=64
    f32x4 acc[4] = {{0,0,0,0},{0,0,0,0},{0,0,0,0},{0,0,0,0}};
    #pragma unroll
    for (int nt = 0; nt < 4; ++nt) {
        s16x8 b_0 = *(const s16x8*)(w1f + (nt * 16 + r16) * 64 + quad * 8);
        s16x8 b_1 = *(const s16x8*)(w1f + (nt * 16 + r16) * 64 + 32 + quad * 8);
        acc[nt] = __builtin_amdgcn_mfma_f32_16x16x32_bf16(a0, b_0, acc[nt], 0, 0, 0);
        acc[nt] = __builtin_amdgcn_mfma_f32_16x16x32_bf16(a1, b_1, acc[nt], 0, 0, 0);
    }
    short* h1w = &s_h1[wave * 16 * H1_PITCH];
    #pragma unroll
    for (int nt = 0; nt < 4; ++nt) {
        float bias = qc[nt * 16 + r16];
        #pragma unroll
        for (int rr = 0; rr < 4; ++rr) {            // D: row=quad*4+rr, col=nt*16+r16
            float v = fmaxf(acc[nt][rr] + bias, 0.f);
            h1w[(quad * 4 + rr) * H1_PITCH + nt * 16 + r16] = f2bf(v);
        }
    }
    __builtin_amdgcn_wave_barrier();                // wave-local LDS RAW; DS in-order per wave

    // H2 = relu(H1 @ w2):  16x32, K=64 ; scores reduced in-register
    s16x8 h0 = *(const s16x8*)&h1w[r16 * H1_PITCH + quad * 8];
    s16x8 h1 = *(const s16x8*)&h1w[r16 * H1_PITCH + 32 + quad * 8];
    f32x4 acc2[2] = {{0,0,0,0},{0,0,0,0}};
    #pragma unroll
    for (int nt = 0; nt < 2; ++nt) {
        s16x8 b_0 = *(const s16x8*)(w2f + (nt * 16 + r16) * 64 + quad * 8);
        s16x8 b_1 = *(const s16x8*)(w2f + (nt * 16 + r16) * 64 + 32 + quad * 8);
        acc2[nt] = __builtin_amdgcn_mfma_f32_16x16x32_bf16(h0, b_0, acc2[nt], 0, 0, 0);
        acc2[nt] = __builtin_amdgcn_mfma_f32_16x16x32_bf16(h1, b_1, acc2[nt], 0, 0, 0);
    }
    const float bias2_lo = ab2[r16], bias2_hi = ab2[16 + r16];
    const float w3_lo    = aw3[r16], w3_hi    = aw3[16 + r16];
    const float b3       = ab3[0];
    #pragma unroll
    for (int rr = 0; rr < 4; ++rr) {
        float p = fmaxf(acc2[0][rr] + bias2_lo, 0.f) * w3_lo
                + fmaxf(acc2[1][rr] + bias2_hi, 0.f) * w3_hi;
        p += __shfl_xor(p, 8);
        p += __shfl_xor(p, 4);
        p += __shfl_xor(p, 2);
        p += __shfl_xor(p, 1);
        int orow = row0 + quad * 4 + rr;
        if (r16 == 0 && orow < 200) scores[orow] = p + b3;
    }
}

// ============================ K4: softmax + pool + final MLP ============================
// one wave per batch row, 4 per block, no __syncthreads
__global__ __launch_bounds__(256)
void din_tail_kernel(const int* __restrict__ item_seq,
                     const int* __restrict__ seq_len_p,
                     const int* __restrict__ tgt_item,
                     const float* __restrict__ ctx_feat,
                     const float* __restrict__ emb,
                     const float* __restrict__ cw,  const float* __restrict__ cb,
                     const float* __restrict__ mw1, const float* __restrict__ mb1,
                     const float* __restrict__ mw2, const float* __restrict__ mb2,
                     const float* __restrict__ mw3, const float* __restrict__ mb3,
                     const short* __restrict__ ws,
                     float* __restrict__ out)
{
    const int t = threadIdx.x, lane = t & 63, wave = t >> 6;
    __shared__ float s_w[4][200];
    __shared__ float s_comb[4][160];
    __shared__ float s_h1[4][128];

    const int b   = blockIdx.x * 4 + wave;
    const int len = seq_len_p[b];
    const short* embbf = ws;
    const float* sc    = (const float*)ws + SC_F + b * 200;

    // ---- softmax over l < len (wave-wide) ----
    float m = -1e30f;
    for (int l = lane; l < len; l += 64) m = fmaxf(m, sc[l]);
    #pragma unroll
    for (int off = 32; off; off >>= 1) m = fmaxf(m, __shfl_xor(m, off));
    float e = 0.f;
    for (int l = lane; l < len; l += 64) {
        float v = __expf(sc[l] - m);
        s_w[wave][l] = v;
        e += v;
    }
    #pragma unroll
    for (int off = 32; off; off >>= 1) e += __shfl_xor(e, off);
    const float inv = 1.f / e;
    __builtin_amdgcn_wave_barrier();

    // ---- pooling: half-wave per row, ushort2 (2 dims/lane) ----
    const int half = lane >> 5, ln = lane & 31;
    float acc0 = 0.f, acc1 = 0.f;
    for (int l = half; l < len; l += 2) {
        int it = item_seq[b * 200 + l];
        unsigned v = *(const unsigned*)(embbf + it * 64 + ln * 2);
        float wgt = s_w[wave][l];
        acc0 += wgt * bf2f((short)(v & 0xffff));
        acc1 += wgt * bf2f((short)(v >> 16));
    }
    acc0 += __shfl_xor(acc0, 32);
    acc1 += __shfl_xor(acc1, 32);
    if (half == 0) {
        s_comb[wave][ln * 2]     = acc0 * inv;
        s_comb[wave][ln * 2 + 1] = acc1 * inv;
    }
    // ---- tgt emb (fp32 exact) + ctx hidden ----
    s_comb[wave][64 + lane] = emb[tgt_item[b] * 64 + lane];
    if (lane < 32) {
        float a = cb[lane];
        #pragma unroll
        for (int k = 0; k < 9; ++k) a += ctx_feat[b * 9 + k] * cw[k * 32 + lane];
        s_comb[wave][128 + lane] = fmaxf(a, 0.f);
    }
    __builtin_amdgcn_wave_barrier();

    // ---- final MLP: 160 -> 128 -> 64 -> 1, per-wave ----
    float A = mb1[lane], B = mb1[lane + 64];
    #pragma unroll 4
    for (int k = 0; k < 160; ++k) {
        float cv = s_comb[wave][k];
        A += cv * mw1[k * 128 + lane];
        B += cv * mw1[k * 128 + lane + 64];
    }
    s_h1[wave][lane]      = fmaxf(A, 0.f);
    s_h1[wave][lane + 64] = fmaxf(B, 0.f);
    __builtin_amdgcn_wave_barrier();

    float h = mb2[lane];
    #pragma unroll 4
    for (int k = 0; k < 128; ++k) h += s_h1[wave][k] * mw2[k * 64 + lane];
    h = fmaxf(h, 0.f);
    float p = h * mw3[lane];
    #pragma unroll
    for (int off = 32; off; off >>= 1) p += __shfl_xor(p, off);
    if (lane == 0) out[b] = 1.f / (1.f + __expf(-(p + mb3[0])));
}

extern "C" void kernel_launch(void* const* d_in, const int* in_sizes, int n_in,
                              void* d_out, int out_size, void* d_ws, size_t ws_size,
                              hipStream_t stream)
{
    const int*   item_seq  = (const int*)  d_in[0];
    // d_in[1] click_sequence: unused by the reference
    const int*   seq_len   = (const int*)  d_in[2];
    const int*   tgt_item  = (const int*)  d_in[3];
    const float* ctx_feat  = (const float*)d_in[4];
    const float* emb       = (const float*)d_in[5];
    const float* aw1 = (const float*)d_in[6];
    const float* ab1 = (const float*)d_in[7];
    const float* aw2 = (const float*)d_in[8];
    const float* ab2 = (const float*)d_in[9];
    const float* aw3 = (const float*)d_in[10];
    const float* ab3 = (const float*)d_in[11];
    const float* cw  = (const float*)d_in[12];
    const float* cb  = (const float*)d_in[13];
    const float* mw1 = (const float*)d_in[14];
    const float* mb1 = (const float*)d_in[15];
    const float* mw2 = (const float*)d_in[16];
    const float* mb2 = (const float*)d_in[17];
    const float* mw3 = (const float*)d_in[18];
    const float* mb3 = (const float*)d_in[19];
    float* out = (float*)d_out;
    short* ws  = (short*)d_ws;

    hipLaunchKernelGGL(din_prep_kernel, dim3(6252), dim3(256), 0, stream,
                       emb, aw1, aw2, ws);
    hipLaunchKernelGGL(din_qc_kernel, dim3(128), dim3(256), 0, stream,
                       tgt_item, ab1, ws);
    hipLaunchKernelGGL(din_att_kernel, dim3(26624), dim3(256), 0, stream,
                       item_seq, seq_len, ab2, aw3, ab3, ws);
    hipLaunchKernelGGL(din_tail_kernel, dim3(2048), dim3(256), 0, stream,
                       item_seq, seq_len, tgt_item, ctx_feat, emb,
                       cw, cb, mw1, mb1, mw2, mb2, mw3, mb3, ws, out);
}

// Round 5
// 236.515 us; speedup vs baseline: 1.2628x; 1.2628x over previous
//
#include <hip/hip_runtime.h>
#include <cmath>

typedef __attribute__((ext_vector_type(8))) short s16x8;   // 8 bf16 = 4 VGPRs (MFMA A/B frag)
typedef __attribute__((ext_vector_type(4))) short s16x4;
typedef __attribute__((ext_vector_type(4))) float f32x4;   // MFMA C/D frag

__device__ __forceinline__ short f2bf(float f) {
    union { float f; unsigned u; } v; v.f = f;
    unsigned r = v.u + 0x7FFFu + ((v.u >> 16) & 1u);   // RNE
    return (short)(r >> 16);
}
__device__ __forceinline__ float bf2f(short s) {
    union { unsigned u; float f; } v; v.u = ((unsigned)(unsigned short)s) << 16;
    return v.f;
}

// ---- ws layout ----
// shorts: [emb_bf16 6,400,064][w1seqT 4096][w1topT 4096][w2T 2048][mw1T 20480][mw2T 8192]
// floats (from short offset 6,438,976 = float 3,219,488): [qc 8192*64][scores 8192*200]
// shorts (from 10,764,352): [comb_bf16 8192*160]  -> total 24,150,144 B
#define EMB_ELEMS 6400064
#define W1SEQ_SH  6400064
#define W1TOP_SH  6404160
#define W2_SH     6408256
#define MW1T_SH   6410304
#define MW2T_SH   6430784
#define QC_F      3219488
#define SC_F      3743776
#define CB_SH     10764352

// ============================ K1: prep ============================
__global__ __launch_bounds__(256)
void din_prep_kernel(const float* __restrict__ emb,
                     const float* __restrict__ aw1,
                     const float* __restrict__ aw2,
                     const float* __restrict__ mw1,
                     const float* __restrict__ mw2,
                     short* __restrict__ ws)
{
    if (blockIdx.x < 6251) {
        long e4 = ((long)blockIdx.x * 256 + threadIdx.x) * 4;
        if (e4 < EMB_ELEMS) {
            float4 v = *(const float4*)(emb + e4);
            s16x4 bv = { f2bf(v.x), f2bf(v.y), f2bf(v.z), f2bf(v.w) };
            *(s16x4*)(ws + e4) = bv;
        }
    } else {
        const int t = threadIdx.x;
        for (int idx = t; idx < 4096; idx += 256) {       // w1seqT[n][k] = aw1[64+k][n]
            int k = idx >> 6, n = idx & 63;
            ws[W1SEQ_SH + n * 64 + k] = f2bf(aw1[(64 + k) * 64 + n]);
        }
        for (int idx = t; idx < 4096; idx += 256) {       // w1topT[n][k] = aw1[k][n]
            int k = idx >> 6, n = idx & 63;
            ws[W1TOP_SH + n * 64 + k] = f2bf(aw1[k * 64 + n]);
        }
        for (int idx = t; idx < 2048; idx += 256) {       // w2T[n][k] = aw2[k][n]
            int k = idx >> 5, n = idx & 31;
            ws[W2_SH + n * 64 + k] = f2bf(aw2[k * 32 + n]);
        }
        for (int idx = t; idx < 20480; idx += 256) {      // mw1T[n][k] = mw1[k][n]  n<128,k<160
            int n = idx / 160, k = idx - n * 160;
            ws[MW1T_SH + idx] = f2bf(mw1[k * 128 + n]);
        }
        for (int idx = t; idx < 8192; idx += 256) {       // mw2T[n][k] = mw2[k][n]  n<64,k<128
            int n = idx >> 7, k = idx & 127;
            ws[MW2T_SH + idx] = f2bf(mw2[k * 64 + n]);
        }
    }
}

// ============================ K2: qc = tgt_emb @ aw1_top + ab1 ============================
__global__ __launch_bounds__(256)
void din_qc_kernel(const int* __restrict__ tgt_item,
                   const float* __restrict__ ab1,
                   short* __restrict__ ws)
{
    const int t = threadIdx.x, lane = t & 63, wave = t >> 6;
    const int quad = lane >> 4, r16 = lane & 15;
    const short* embbf = ws;
    const short* w1t   = ws + W1TOP_SH;
    float* qc = (float*)ws + QC_F;

    const int b0 = (blockIdx.x * 4 + wave) * 16;
    const int it = tgt_item[b0 + r16];
    const short* rp = embbf + it * 64 + quad * 8;
    s16x8 a0 = *(const s16x8*)(rp);
    s16x8 a1 = *(const s16x8*)(rp + 32);

    f32x4 acc[4] = {{0,0,0,0},{0,0,0,0},{0,0,0,0},{0,0,0,0}};
    #pragma unroll
    for (int nt = 0; nt < 4; ++nt) {
        s16x8 b_0 = *(const s16x8*)(w1t + (nt * 16 + r16) * 64 + quad * 8);
        s16x8 b_1 = *(const s16x8*)(w1t + (nt * 16 + r16) * 64 + 32 + quad * 8);
        acc[nt] = __builtin_amdgcn_mfma_f32_16x16x32_bf16(a0, b_0, acc[nt], 0, 0, 0);
        acc[nt] = __builtin_amdgcn_mfma_f32_16x16x32_bf16(a1, b_1, acc[nt], 0, 0, 0);
    }
    #pragma unroll
    for (int nt = 0; nt < 4; ++nt) {
        float bias = ab1[nt * 16 + r16];
        #pragma unroll
        for (int rr = 0; rr < 4; ++rr)   // D: row=quad*4+rr, col=nt*16+r16
            qc[(b0 + quad * 4 + rr) * 64 + nt * 16 + r16] = acc[nt][rr] + bias;
    }
}

// ============================ K3: attention scores, 32 rows (2 chunks) per wave ============
#define H1_PITCH 72
__global__ __launch_bounds__(256)
void din_att_kernel(const int* __restrict__ item_seq,
                    const int* __restrict__ seq_len_p,
                    const float* __restrict__ ab2,
                    const float* __restrict__ aw3, const float* __restrict__ ab3,
                    short* __restrict__ ws)
{
    const int t = threadIdx.x, lane = t & 63, wave = t >> 6;
    const int quad = lane >> 4, r16 = lane & 15;
    __shared__ short s_w1[4096];              // 8 KB, frag layout [n][k]
    __shared__ short s_w2[2048];              // 4 KB
    __shared__ short s_h1[4][16 * H1_PITCH];  // 9 KB, per-wave H1 buffer

    // stage weights once per block (L2-hot source)
    {
        const s16x8* src1 = (const s16x8*)(ws + W1SEQ_SH);
        s16x8* dst1 = (s16x8*)s_w1;
        for (int i = t; i < 512; i += 256) dst1[i] = src1[i];
        const s16x8* src2 = (const s16x8*)(ws + W2_SH);
        if (t < 256) ((s16x8*)s_w2)[t] = src2[t];
    }
    __syncthreads();

    const unsigned s = blockIdx.x * 4 + wave;     // 0 .. 57343
    const int b   = s / 7u;
    const int cp  = s - b * 7u;                   // chunk-pair 0..6
    const int len = seq_len_p[b];
    const int row0 = cp * 32;
    if (row0 >= len) return;                      // wave-uniform exit (after barrier)
    const bool live1 = (row0 + 16) < len;

    const short* embbf = ws;
    const float* qc    = (const float*)ws + QC_F + b * 64;
    float* scores      = (float*)ws + SC_F + b * 200;

    // issue all gathers up front (4 x 16B per lane, 32 rows)
    int r0 = row0 + r16;      if (r0 > 199) r0 = 199;
    int r1 = row0 + 16 + r16; if (r1 > 199) r1 = 199;
    const int it0 = item_seq[b * 200 + r0];
    s16x8 a00 = *(const s16x8*)(embbf + it0 * 64 + quad * 8);
    s16x8 a01 = *(const s16x8*)(embbf + it0 * 64 + 32 + quad * 8);
    s16x8 a10 = {}, a11 = {};
    if (live1) {
        const int it1 = item_seq[b * 200 + r1];
        a10 = *(const s16x8*)(embbf + it1 * 64 + quad * 8);
        a11 = *(const s16x8*)(embbf + it1 * 64 + 32 + quad * 8);
    }

    // w2 frags in registers (shared by both chunks)
    s16x8 w2r[4];
    #pragma unroll
    for (int nt = 0; nt < 2; ++nt) {
        w2r[nt * 2]     = *(const s16x8*)(s_w2 + (nt * 16 + r16) * 64 + quad * 8);
        w2r[nt * 2 + 1] = *(const s16x8*)(s_w2 + (nt * 16 + r16) * 64 + 32 + quad * 8);
    }
    float qcv[4];
    #pragma unroll
    for (int nt = 0; nt < 4; ++nt) qcv[nt] = qc[nt * 16 + r16];
    const float bias2_lo = ab2[r16], bias2_hi = ab2[16 + r16];
    const float w3_lo    = aw3[r16], w3_hi    = aw3[16 + r16];
    const float b3       = ab3[0];

    // H1 for both chunks (w1 frags read once from LDS, reused)
    f32x4 acc0[4] = {{0,0,0,0},{0,0,0,0},{0,0,0,0},{0,0,0,0}};
    f32x4 acc1[4] = {{0,0,0,0},{0,0,0,0},{0,0,0,0},{0,0,0,0}};
    #pragma unroll
    for (int nt = 0; nt < 4; ++nt) {
        s16x8 b_0 = *(const s16x8*)(s_w1 + (nt * 16 + r16) * 64 + quad * 8);
        s16x8 b_1 = *(const s16x8*)(s_w1 + (nt * 16 + r16) * 64 + 32 + quad * 8);
        acc0[nt] = __builtin_amdgcn_mfma_f32_16x16x32_bf16(a00, b_0, acc0[nt], 0, 0, 0);
        acc0[nt] = __builtin_amdgcn_mfma_f32_16x16x32_bf16(a01, b_1, acc0[nt], 0, 0, 0);
        if (live1) {
            acc1[nt] = __builtin_amdgcn_mfma_f32_16x16x32_bf16(a10, b_0, acc1[nt], 0, 0, 0);
            acc1[nt] = __builtin_amdgcn_mfma_f32_16x16x32_bf16(a11, b_1, acc1[nt], 0, 0, 0);
        }
    }

    short* h1w = s_h1[wave];
    #pragma unroll
    for (int ck = 0; ck < 2; ++ck) {
        if (ck == 1 && !live1) break;
        const f32x4* acc = (ck == 0) ? acc0 : acc1;
        const int rbase = row0 + ck * 16;
        #pragma unroll
        for (int nt = 0; nt < 4; ++nt)
            #pragma unroll
            for (int rr = 0; rr < 4; ++rr) {          // D: row=quad*4+rr, col=nt*16+r16
                float v = fmaxf(acc[nt][rr] + qcv[nt], 0.f);
                h1w[(quad * 4 + rr) * H1_PITCH + nt * 16 + r16] = f2bf(v);
            }
        __builtin_amdgcn_wave_barrier();              // wave-local LDS RAW

        s16x8 h0  = *(const s16x8*)&h1w[r16 * H1_PITCH + quad * 8];
        s16x8 h1v = *(const s16x8*)&h1w[r16 * H1_PITCH + 32 + quad * 8];
        f32x4 c2[2] = {{0,0,0,0},{0,0,0,0}};
        #pragma unroll
        for (int nt = 0; nt < 2; ++nt) {
            c2[nt] = __builtin_amdgcn_mfma_f32_16x16x32_bf16(h0,  w2r[nt * 2],     c2[nt], 0, 0, 0);
            c2[nt] = __builtin_amdgcn_mfma_f32_16x16x32_bf16(h1v, w2r[nt * 2 + 1], c2[nt], 0, 0, 0);
        }
        #pragma unroll
        for (int rr = 0; rr < 4; ++rr) {
            float p = fmaxf(c2[0][rr] + bias2_lo, 0.f) * w3_lo
                    + fmaxf(c2[1][rr] + bias2_hi, 0.f) * w3_hi;
            p += __shfl_xor(p, 8);
            p += __shfl_xor(p, 4);
            p += __shfl_xor(p, 2);
            p += __shfl_xor(p, 1);
            int orow = rbase + quad * 4 + rr;
            if (r16 == 0 && orow < 200) scores[orow] = p + b3;
        }
        __builtin_amdgcn_wave_barrier();
    }
}

// ============================ K4a: softmax + pooling -> comb (bf16) ============================
__global__ __launch_bounds__(256)
void din_pool_kernel(const int* __restrict__ item_seq,
                     const int* __restrict__ seq_len_p,
                     const int* __restrict__ tgt_item,
                     const float* __restrict__ ctx_feat,
                     const float* __restrict__ cw,  const float* __restrict__ cb,
                     short* __restrict__ ws)
{
    const int t = threadIdx.x, lane = t & 63, wave = t >> 6;
    const int quad = lane >> 4, r16 = lane & 15;
    __shared__ float s_w[4][200];

    const int b   = blockIdx.x * 4 + wave;
    const int len = seq_len_p[b];
    const short* embbf = ws;
    const float* sc    = (const float*)ws + SC_F + b * 200;
    short* comb        = ws + CB_SH + b * 160;

    // softmax over l < len
    float m = -1e30f;
    for (int l = lane; l < len; l += 64) m = fmaxf(m, sc[l]);
    #pragma unroll
    for (int off = 32; off; off >>= 1) m = fmaxf(m, __shfl_xor(m, off));
    float e = 0.f;
    for (int l = lane; l < len; l += 64) {
        float v = __expf(sc[l] - m);
        s_w[wave][l] = v;
        e += v;
    }
    #pragma unroll
    for (int off = 32; off; off >>= 1) e += __shfl_xor(e, off);
    const float inv = 1.f / e;
    __builtin_amdgcn_wave_barrier();

    // pooling: 4 rows/iter; lane = (row quad, dims r16*4..+3); one 128B line per row
    float a0 = 0.f, a1 = 0.f, a2 = 0.f, a3 = 0.f;
    for (int l = quad; l < len; l += 4) {
        int it = item_seq[b * 200 + l];                       // broadcast within quad
        s16x4 v = *(const s16x4*)(embbf + it * 64 + r16 * 4);
        float wg = s_w[wave][l];
        a0 += wg * bf2f(v.x);
        a1 += wg * bf2f(v.y);
        a2 += wg * bf2f(v.z);
        a3 += wg * bf2f(v.w);
    }
    a0 += __shfl_xor(a0, 16); a0 += __shfl_xor(a0, 32);
    a1 += __shfl_xor(a1, 16); a1 += __shfl_xor(a1, 32);
    a2 += __shfl_xor(a2, 16); a2 += __shfl_xor(a2, 32);
    a3 += __shfl_xor(a3, 16); a3 += __shfl_xor(a3, 32);
    if (quad == 0) {
        s16x4 bv = { f2bf(a0 * inv), f2bf(a1 * inv), f2bf(a2 * inv), f2bf(a3 * inv) };
        *(s16x4*)(comb + r16 * 4) = bv;
    }
    // tgt emb (already bf16) + ctx hidden
    comb[64 + lane] = embbf[tgt_item[b] * 64 + lane];
    if (lane < 32) {
        float a = cb[lane];
        #pragma unroll
        for (int k = 0; k < 9; ++k) a += ctx_feat[b * 9 + k] * cw[k * 32 + lane];
        comb[128 + lane] = f2bf(fmaxf(a, 0.f));
    }
}

// ============================ K4b: batched final MLP via MFMA (16 rows/wave) ==================
__global__ __launch_bounds__(256)
void din_mlp_kernel(const float* __restrict__ mb1,
                    const float* __restrict__ mb2,
                    const float* __restrict__ mw3, const float* __restrict__ mb3,
                    const short* __restrict__ ws,
                    float* __restrict__ out)
{
    const int t = threadIdx.x, lane = t & 63, wave = t >> 6;
    const int quad = lane >> 4, r16 = lane & 15;
    __shared__ short s_h1[4][16 * 136];   // pitch 136 shorts (272B rows)
    __shared__ short s_h2[4][16 * 72];

    const int b0 = (blockIdx.x * 4 + wave) * 16;
    const short* comb = ws + CB_SH;
    const short* w1   = ws + MW1T_SH;
    const short* w2   = ws + MW2T_SH;

    // layer1: (16x160) @ (160x128), K=160 in 5 steps
    s16x8 a[5];
    #pragma unroll
    for (int ks = 0; ks < 5; ++ks)
        a[ks] = *(const s16x8*)(comb + (b0 + r16) * 160 + ks * 32 + quad * 8);
    f32x4 acc[8] = {{0,0,0,0},{0,0,0,0},{0,0,0,0},{0,0,0,0},{0,0,0,0},{0,0,0,0},{0,0,0,0},{0,0,0,0}};
    #pragma unroll
    for (int nt = 0; nt < 8; ++nt)
        #pragma unroll
        for (int ks = 0; ks < 5; ++ks) {
            s16x8 bf = *(const s16x8*)(w1 + (nt * 16 + r16) * 160 + ks * 32 + quad * 8);
            acc[nt] = __builtin_amdgcn_mfma_f32_16x16x32_bf16(a[ks], bf, acc[nt], 0, 0, 0);
        }
    #pragma unroll
    for (int nt = 0; nt < 8; ++nt) {
        float bias = mb1[nt * 16 + r16];
        #pragma unroll
        for (int rr = 0; rr < 4; ++rr)
            s_h1[wave][(quad * 4 + rr) * 136 + nt * 16 + r16] = f2bf(fmaxf(acc[nt][rr] + bias, 0.f));
    }
    __builtin_amdgcn_wave_barrier();

    // layer2: (16x128) @ (128x64), K=128 in 4 steps
    s16x8 a2[4];
    #pragma unroll
    for (int ks = 0; ks < 4; ++ks)
        a2[ks] = *(const s16x8*)&s_h1[wave][r16 * 136 + ks * 32 + quad * 8];
    f32x4 acc2[4] = {{0,0,0,0},{0,0,0,0},{0,0,0,0},{0,0,0,0}};
    #pragma unroll
    for (int nt = 0; nt < 4; ++nt)
        #pragma unroll
        for (int ks = 0; ks < 4; ++ks) {
            s16x8 bf = *(const s16x8*)(w2 + (nt * 16 + r16) * 128 + ks * 32 + quad * 8);
            acc2[nt] = __builtin_amdgcn_mfma_f32_16x16x32_bf16(a2[ks], bf, acc2[nt], 0, 0, 0);
        }
    #pragma unroll
    for (int nt = 0; nt < 4; ++nt) {
        float bias = mb2[nt * 16 + r16];
        #pragma unroll
        for (int rr = 0; rr < 4; ++rr)
            s_h2[wave][(quad * 4 + rr) * 72 + nt * 16 + r16] = f2bf(fmaxf(acc2[nt][rr] + bias, 0.f));
    }
    __builtin_amdgcn_wave_barrier();

    // layer3: (16x64) @ (64x1) + sigmoid; lane=(row r16, dim-group quad)
    float p = 0.f;
    #pragma unroll
    for (int j = 0; j < 16; ++j)
        p += bf2f(s_h2[wave][r16 * 72 + quad * 16 + j]) * mw3[quad * 16 + j];
    p += __shfl_xor(p, 16);
    p += __shfl_xor(p, 32);
    if (quad == 0) out[b0 + r16] = 1.f / (1.f + __expf(-(p + mb3[0])));
}

extern "C" void kernel_launch(void* const* d_in, const int* in_sizes, int n_in,
                              void* d_out, int out_size, void* d_ws, size_t ws_size,
                              hipStream_t stream)
{
    const int*   item_seq  = (const int*)  d_in[0];
    // d_in[1] click_sequence: unused by the reference
    const int*   seq_len   = (const int*)  d_in[2];
    const int*   tgt_item  = (const int*)  d_in[3];
    const float* ctx_feat  = (const float*)d_in[4];
    const float* emb       = (const float*)d_in[5];
    const float* aw1 = (const float*)d_in[6];
    const float* ab1 = (const float*)d_in[7];
    const float* aw2 = (const float*)d_in[8];
    const float* ab2 = (const float*)d_in[9];
    const float* aw3 = (const float*)d_in[10];
    const float* ab3 = (const float*)d_in[11];
    const float* cw  = (const float*)d_in[12];
    const float* cb  = (const float*)d_in[13];
    const float* mw1 = (const float*)d_in[14];
    const float* mb1 = (const float*)d_in[15];
    const float* mw2 = (const float*)d_in[16];
    const float* mb2 = (const float*)d_in[17];
    const float* mw3 = (const float*)d_in[18];
    const float* mb3 = (const float*)d_in[19];
    float* out = (float*)d_out;
    short* ws  = (short*)d_ws;

    hipLaunchKernelGGL(din_prep_kernel, dim3(6252), dim3(256), 0, stream,
                       emb, aw1, aw2, mw1, mw2, ws);
    hipLaunchKernelGGL(din_qc_kernel, dim3(128), dim3(256), 0, stream,
                       tgt_item, ab1, ws);
    hipLaunchKernelGGL(din_att_kernel, dim3(14336), dim3(256), 0, stream,
                       item_seq, seq_len, ab2, aw3, ab3, ws);
    hipLaunchKernelGGL(din_pool_kernel, dim3(2048), dim3(256), 0, stream,
                       item_seq, seq_len, tgt_item, ctx_feat, cw, cb, ws);
    hipLaunchKernelGGL(din_mlp_kernel, dim3(128), dim3(256), 0, stream,
                       mb1, mb2, mw3, mb3, ws, out);
}

// Round 6
// 197.775 us; speedup vs baseline: 1.5101x; 1.1959x over previous
//
#include <hip/hip_runtime.h>
#include <cmath>

typedef __attribute__((ext_vector_type(8))) short s16x8;   // 8 bf16 = 4 VGPRs (MFMA A/B frag)
typedef __attribute__((ext_vector_type(4))) short s16x4;
typedef __attribute__((ext_vector_type(4))) float f32x4;   // MFMA C/D frag

__device__ __forceinline__ short f2bf(float f) {
    union { float f; unsigned u; } v; v.f = f;
    unsigned r = v.u + 0x7FFFu + ((v.u >> 16) & 1u);   // RNE
    return (short)(r >> 16);
}
__device__ __forceinline__ float bf2f(short s) {
    union { unsigned u; float f; } v; v.u = ((unsigned)(unsigned short)s) << 16;
    return v.f;
}

// ---- ws layout (same offsets as round 5; weight blobs now frag-linear) ----
// shorts: [emb_bf16 6,400,064][w1seqF 4096][w1topF 4096][w2F 2048][mw1F 20480][mw2F 8192]
// floats (from float offset 3,219,488): [qc 8192*64][scores 8192*200]
// shorts (from 10,764,352): [comb_bf16 8192*160]
#define EMB_ELEMS 6400064
#define W1SEQ_SH  6400064
#define W1TOP_SH  6404160
#define W2_SH     6408256
#define MW1T_SH   6410304
#define MW2T_SH   6430784
#define QC_F      3219488
#define SC_F      3743776
#define CB_SH     10764352

// frag-linear index helper (prep side): idx = (frag*64 + lane)*8 + j
// att/qc/mlp side: frag (nt,ks) base = ((nt*KS + ks)*64 + lane)*8

// ============================ K1: prep ============================
__global__ __launch_bounds__(256)
void din_prep_kernel(const float* __restrict__ emb,
                     const float* __restrict__ aw1,
                     const float* __restrict__ aw2,
                     const float* __restrict__ mw1,
                     const float* __restrict__ mw2,
                     short* __restrict__ ws)
{
    const int bid = blockIdx.x;
    const int t = threadIdx.x;
    if (bid < 6251) {
        long e4 = ((long)bid * 256 + t) * 4;
        if (e4 < EMB_ELEMS) {
            float4 v = *(const float4*)(emb + e4);
            s16x4 bv = { f2bf(v.x), f2bf(v.y), f2bf(v.z), f2bf(v.w) };
            *(s16x4*)(ws + e4) = bv;
        }
        return;
    }
    const int wb = bid - 6251;   // 0..7
    if (wb == 0) {               // w1seq frag-linear: frag = nt*2+ks (nt<4,ks<2)
        for (int idx = t; idx < 4096; idx += 256) {
            int j = idx & 7, lane = (idx >> 3) & 63, fr = idx >> 9;
            int n = (fr >> 1) * 16 + (lane & 15);
            int k = (fr & 1) * 32 + (lane >> 4) * 8 + j;
            ws[W1SEQ_SH + idx] = f2bf(aw1[(64 + k) * 64 + n]);
        }
    } else if (wb == 1) {        // w1top frag-linear
        for (int idx = t; idx < 4096; idx += 256) {
            int j = idx & 7, lane = (idx >> 3) & 63, fr = idx >> 9;
            int n = (fr >> 1) * 16 + (lane & 15);
            int k = (fr & 1) * 32 + (lane >> 4) * 8 + j;
            ws[W1TOP_SH + idx] = f2bf(aw1[k * 64 + n]);
        }
    } else if (wb == 2) {        // w2 frag-linear: frag = nt*2+ks (nt<2,ks<2)
        for (int idx = t; idx < 2048; idx += 256) {
            int j = idx & 7, lane = (idx >> 3) & 63, fr = idx >> 9;
            int n = (fr >> 1) * 16 + (lane & 15);
            int k = (fr & 1) * 32 + (lane >> 4) * 8 + j;
            ws[W2_SH + idx] = f2bf(aw2[k * 32 + n]);
        }
    } else if (wb == 3) {        // mw2 frag-linear: frag = nt*4+ks (nt<4,ks<4)
        for (int idx = t; idx < 8192; idx += 256) {
            int j = idx & 7, lane = (idx >> 3) & 63, fr = idx >> 9;
            int n = (fr >> 2) * 16 + (lane & 15);
            int k = (fr & 3) * 32 + (lane >> 4) * 8 + j;
            ws[MW2T_SH + idx] = f2bf(mw2[k * 64 + n]);
        }
    } else {                     // wb 4..7: mw1 frag-linear quarter: frag = nt*5+ks (nt<8,ks<5)
        const int base = (wb - 4) * 5120;
        for (int ii = t; ii < 5120; ii += 256) {
            int idx = base + ii;
            int j = idx & 7, lane = (idx >> 3) & 63, fr = idx >> 9;
            int nt = fr / 5, ks = fr - nt * 5;
            int n = nt * 16 + (lane & 15);
            int k = ks * 32 + (lane >> 4) * 8 + j;
            ws[MW1T_SH + idx] = f2bf(mw1[k * 128 + n]);
        }
    }
}

// ============================ K2: qc = tgt_emb @ aw1_top + ab1 ============================
__global__ __launch_bounds__(256)
void din_qc_kernel(const int* __restrict__ tgt_item,
                   const float* __restrict__ ab1,
                   short* __restrict__ ws)
{
    const int t = threadIdx.x, lane = t & 63, wave = t >> 6;
    const int quad = lane >> 4, r16 = lane & 15;
    const short* embbf = ws;
    const short* w1t   = ws + W1TOP_SH;
    float* qc = (float*)ws + QC_F;

    const int b0 = (blockIdx.x * 4 + wave) * 16;
    const int it = tgt_item[b0 + r16];
    const short* rp = embbf + it * 64 + quad * 8;
    s16x8 a0 = *(const s16x8*)(rp);
    s16x8 a1 = *(const s16x8*)(rp + 32);

    f32x4 acc[4] = {{0,0,0,0},{0,0,0,0},{0,0,0,0},{0,0,0,0}};
    #pragma unroll
    for (int nt = 0; nt < 4; ++nt) {
        s16x8 b_0 = *(const s16x8*)(w1t + ((nt * 2 + 0) * 64 + lane) * 8);
        s16x8 b_1 = *(const s16x8*)(w1t + ((nt * 2 + 1) * 64 + lane) * 8);
        acc[nt] = __builtin_amdgcn_mfma_f32_16x16x32_bf16(a0, b_0, acc[nt], 0, 0, 0);
        acc[nt] = __builtin_amdgcn_mfma_f32_16x16x32_bf16(a1, b_1, acc[nt], 0, 0, 0);
    }
    #pragma unroll
    for (int nt = 0; nt < 4; ++nt) {
        float bias = ab1[nt * 16 + r16];
        #pragma unroll
        for (int rr = 0; rr < 4; ++rr)   // D: row=quad*4+rr, col=nt*16+r16
            qc[(b0 + quad * 4 + rr) * 64 + nt * 16 + r16] = acc[nt][rr] + bias;
    }
}

// ============================ K3: attention scores — 64 rows per wave ============================
#define H1_PITCH 72
__global__ __launch_bounds__(256)
void din_att_kernel(const int* __restrict__ item_seq,
                    const int* __restrict__ seq_len_p,
                    const float* __restrict__ ab2,
                    const float* __restrict__ aw3, const float* __restrict__ ab3,
                    short* __restrict__ ws)
{
    const int t = threadIdx.x, lane = t & 63, wave = t >> 6;
    const int quad = lane >> 4, r16 = lane & 15;
    __shared__ short s_w1[4096];              // 8 KB, frag-linear
    __shared__ short s_h1[4][16 * H1_PITCH];  // 9 KB

    // stage w1seq frags (linear copy, conflict-free)
    {
        const s16x8* src = (const s16x8*)(ws + W1SEQ_SH);
        s16x8* dst = (s16x8*)s_w1;
        for (int i = t; i < 512; i += 256) dst[i] = src[i];
    }
    __syncthreads();

    const int b    = blockIdx.x;
    const int len  = seq_len_p[b];
    const int row0 = wave * 64;
    if (row0 >= len) return;                  // wave-uniform exit (after the one barrier)
    const int nc = min(4, (len - row0 + 15) >> 4);

    const short* embbf = ws;
    const float* qc    = (const float*)ws + QC_F + b * 64;
    float* scores      = (float*)ws + SC_F + b * 200;

    // ---- issue all gathers up front (up to 8 x 16B per lane) ----
    s16x8 af[4][2];
    #pragma unroll
    for (int ck = 0; ck < 4; ++ck) {
        if (ck < nc) {
            int r = row0 + ck * 16 + r16; if (r > 199) r = 199;
            const int it = item_seq[b * 200 + r];
            af[ck][0] = *(const s16x8*)(embbf + it * 64 + quad * 8);
            af[ck][1] = *(const s16x8*)(embbf + it * 64 + 32 + quad * 8);
        }
    }
    // ---- w2 frags from global (frag-linear, coalesced 1KB bursts) ----
    s16x8 w2r[4];
    #pragma unroll
    for (int fr = 0; fr < 4; ++fr)
        w2r[fr] = *(const s16x8*)(ws + W2_SH + (fr * 64 + lane) * 8);

    float qcv[4];
    #pragma unroll
    for (int nt = 0; nt < 4; ++nt) qcv[nt] = qc[nt * 16 + r16];
    const float bias2_lo = ab2[r16], bias2_hi = ab2[16 + r16];
    const float w3_lo    = aw3[r16], w3_hi    = aw3[16 + r16];
    const float b3       = ab3[0];
    short* h1w = s_h1[wave];

    #pragma unroll
    for (int ck = 0; ck < 4; ++ck) {
        if (ck >= nc) break;
        // H1 = relu(seq16 @ w1seq + qc): 8 MFMA, B-frags from LDS at lane*16 (conflict-free)
        f32x4 acc[4] = {{0,0,0,0},{0,0,0,0},{0,0,0,0},{0,0,0,0}};
        #pragma unroll
        for (int nt = 0; nt < 4; ++nt) {
            s16x8 b_0 = *(const s16x8*)&s_w1[((nt * 2 + 0) * 64 + lane) * 8];
            s16x8 b_1 = *(const s16x8*)&s_w1[((nt * 2 + 1) * 64 + lane) * 8];
            acc[nt] = __builtin_amdgcn_mfma_f32_16x16x32_bf16(af[ck][0], b_0, acc[nt], 0, 0, 0);
            acc[nt] = __builtin_amdgcn_mfma_f32_16x16x32_bf16(af[ck][1], b_1, acc[nt], 0, 0, 0);
        }
        #pragma unroll
        for (int nt = 0; nt < 4; ++nt)
            #pragma unroll
            for (int rr = 0; rr < 4; ++rr) {          // D: row=quad*4+rr, col=nt*16+r16
                float v = fmaxf(acc[nt][rr] + qcv[nt], 0.f);
                h1w[(quad * 4 + rr) * H1_PITCH + nt * 16 + r16] = f2bf(v);
            }
        __builtin_amdgcn_wave_barrier();              // wave-local LDS RAW

        // H2 = relu(H1 @ w2): 4 MFMA; scores reduced in-register
        s16x8 h0  = *(const s16x8*)&h1w[r16 * H1_PITCH + quad * 8];
        s16x8 h1v = *(const s16x8*)&h1w[r16 * H1_PITCH + 32 + quad * 8];
        f32x4 c2[2] = {{0,0,0,0},{0,0,0,0}};
        #pragma unroll
        for (int nt = 0; nt < 2; ++nt) {
            c2[nt] = __builtin_amdgcn_mfma_f32_16x16x32_bf16(h0,  w2r[nt * 2],     c2[nt], 0, 0, 0);
            c2[nt] = __builtin_amdgcn_mfma_f32_16x16x32_bf16(h1v, w2r[nt * 2 + 1], c2[nt], 0, 0, 0);
        }
        #pragma unroll
        for (int rr = 0; rr < 4; ++rr) {
            float p = fmaxf(c2[0][rr] + bias2_lo, 0.f) * w3_lo
                    + fmaxf(c2[1][rr] + bias2_hi, 0.f) * w3_hi;
            p += __shfl_xor(p, 8);
            p += __shfl_xor(p, 4);
            p += __shfl_xor(p, 2);
            p += __shfl_xor(p, 1);
            int orow = row0 + ck * 16 + quad * 4 + rr;
            if (r16 == 0 && orow < 200) scores[orow] = p + b3;
        }
        __builtin_amdgcn_wave_barrier();
    }
}

// ============================ K4a: softmax + pooling -> comb (bf16) ============================
__global__ __launch_bounds__(256)
void din_pool_kernel(const int* __restrict__ item_seq,
                     const int* __restrict__ seq_len_p,
                     const int* __restrict__ tgt_item,
                     const float* __restrict__ ctx_feat,
                     const float* __restrict__ cw,  const float* __restrict__ cb,
                     short* __restrict__ ws)
{
    const int t = threadIdx.x, lane = t & 63, wave = t >> 6;
    const int quad = lane >> 4, r16 = lane & 15;
    __shared__ float s_w[4][200];

    const int b   = blockIdx.x * 4 + wave;
    const int len = seq_len_p[b];
    const short* embbf = ws;
    const float* sc    = (const float*)ws + SC_F + b * 200;
    short* comb        = ws + CB_SH + b * 160;

    // softmax over l < len
    float m = -1e30f;
    for (int l = lane; l < len; l += 64) m = fmaxf(m, sc[l]);
    #pragma unroll
    for (int off = 32; off; off >>= 1) m = fmaxf(m, __shfl_xor(m, off));
    float e = 0.f;
    for (int l = lane; l < len; l += 64) {
        float v = __expf(sc[l] - m);
        s_w[wave][l] = v;
        e += v;
    }
    #pragma unroll
    for (int off = 32; off; off >>= 1) e += __shfl_xor(e, off);
    const float inv = 1.f / e;
    __builtin_amdgcn_wave_barrier();

    // pooling: 8 rows per iteration in flight (2 per quad); lane=(row quad, dims r16*4..+3)
    float a0 = 0.f, a1 = 0.f, a2 = 0.f, a3 = 0.f;
    for (int l = quad; l < len; l += 8) {
        const int it0 = item_seq[b * 200 + l];
        s16x4 v0 = *(const s16x4*)(embbf + it0 * 64 + r16 * 4);
        const int l1 = l + 4;
        const bool live1 = l1 < len;
        s16x4 v1 = {};
        if (live1) {
            const int it1 = item_seq[b * 200 + l1];
            v1 = *(const s16x4*)(embbf + it1 * 64 + r16 * 4);
        }
        const float w0 = s_w[wave][l];
        const float w1 = live1 ? s_w[wave][l1] : 0.f;
        a0 += w0 * bf2f(v0.x) + w1 * bf2f(v1.x);
        a1 += w0 * bf2f(v0.y) + w1 * bf2f(v1.y);
        a2 += w0 * bf2f(v0.z) + w1 * bf2f(v1.z);
        a3 += w0 * bf2f(v0.w) + w1 * bf2f(v1.w);
    }
    a0 += __shfl_xor(a0, 16); a0 += __shfl_xor(a0, 32);
    a1 += __shfl_xor(a1, 16); a1 += __shfl_xor(a1, 32);
    a2 += __shfl_xor(a2, 16); a2 += __shfl_xor(a2, 32);
    a3 += __shfl_xor(a3, 16); a3 += __shfl_xor(a3, 32);
    if (quad == 0) {
        s16x4 bv = { f2bf(a0 * inv), f2bf(a1 * inv), f2bf(a2 * inv), f2bf(a3 * inv) };
        *(s16x4*)(comb + r16 * 4) = bv;
    }
    // tgt emb (bf16) + ctx hidden
    comb[64 + lane] = embbf[tgt_item[b] * 64 + lane];
    if (lane < 32) {
        float a = cb[lane];
        #pragma unroll
        for (int k = 0; k < 9; ++k) a += ctx_feat[b * 9 + k] * cw[k * 32 + lane];
        comb[128 + lane] = f2bf(fmaxf(a, 0.f));
    }
}

// ============================ K4b: batched final MLP via MFMA (16 rows/wave) ==================
__global__ __launch_bounds__(256)
void din_mlp_kernel(const float* __restrict__ mb1,
                    const float* __restrict__ mb2,
                    const float* __restrict__ mw3, const float* __restrict__ mb3,
                    const short* __restrict__ ws,
                    float* __restrict__ out)
{
    const int t = threadIdx.x, lane = t & 63, wave = t >> 6;
    const int quad = lane >> 4, r16 = lane & 15;
    __shared__ short s_h1[4][16 * 136];
    __shared__ short s_h2[4][16 * 72];

    const int b0 = (blockIdx.x * 4 + wave) * 16;
    const short* comb = ws + CB_SH;
    const short* w1   = ws + MW1T_SH;
    const short* w2   = ws + MW2T_SH;

    // layer1: (16x160) @ (160x128), K=160 in 5 steps; B-frags frag-linear (coalesced)
    s16x8 a[5];
    #pragma unroll
    for (int ks = 0; ks < 5; ++ks)
        a[ks] = *(const s16x8*)(comb + (b0 + r16) * 160 + ks * 32 + quad * 8);
    f32x4 acc[8] = {{0,0,0,0},{0,0,0,0},{0,0,0,0},{0,0,0,0},{0,0,0,0},{0,0,0,0},{0,0,0,0},{0,0,0,0}};
    #pragma unroll
    for (int nt = 0; nt < 8; ++nt)
        #pragma unroll
        for (int ks = 0; ks < 5; ++ks) {
            s16x8 bf = *(const s16x8*)(w1 + ((nt * 5 + ks) * 64 + lane) * 8);
            acc[nt] = __builtin_amdgcn_mfma_f32_16x16x32_bf16(a[ks], bf, acc[nt], 0, 0, 0);
        }
    #pragma unroll
    for (int nt = 0; nt < 8; ++nt) {
        float bias = mb1[nt * 16 + r16];
        #pragma unroll
        for (int rr = 0; rr < 4; ++rr)
            s_h1[wave][(quad * 4 + rr) * 136 + nt * 16 + r16] = f2bf(fmaxf(acc[nt][rr] + bias, 0.f));
    }
    __builtin_amdgcn_wave_barrier();

    // layer2: (16x128) @ (128x64), K=128 in 4 steps
    s16x8 a2[4];
    #pragma unroll
    for (int ks = 0; ks < 4; ++ks)
        a2[ks] = *(const s16x8*)&s_h1[wave][r16 * 136 + ks * 32 + quad * 8];
    f32x4 acc2[4] = {{0,0,0,0},{0,0,0,0},{0,0,0,0},{0,0,0,0}};
    #pragma unroll
    for (int nt = 0; nt < 4; ++nt)
        #pragma unroll
        for (int ks = 0; ks < 4; ++ks) {
            s16x8 bf = *(const s16x8*)(w2 + ((nt * 4 + ks) * 64 + lane) * 8);
            acc2[nt] = __builtin_amdgcn_mfma_f32_16x16x32_bf16(a2[ks], bf, acc2[nt], 0, 0, 0);
        }
    #pragma unroll
    for (int nt = 0; nt < 4; ++nt) {
        float bias = mb2[nt * 16 + r16];
        #pragma unroll
        for (int rr = 0; rr < 4; ++rr)
            s_h2[wave][(quad * 4 + rr) * 72 + nt * 16 + r16] = f2bf(fmaxf(acc2[nt][rr] + bias, 0.f));
    }
    __builtin_amdgcn_wave_barrier();

    // layer3: (16x64) @ (64x1) + sigmoid; lane=(row r16, dim-group quad)
    float p = 0.f;
    #pragma unroll
    for (int j = 0; j < 16; ++j)
        p += bf2f(s_h2[wave][r16 * 72 + quad * 16 + j]) * mw3[quad * 16 + j];
    p += __shfl_xor(p, 16);
    p += __shfl_xor(p, 32);
    if (quad == 0) out[b0 + r16] = 1.f / (1.f + __expf(-(p + mb3[0])));
}

extern "C" void kernel_launch(void* const* d_in, const int* in_sizes, int n_in,
                              void* d_out, int out_size, void* d_ws, size_t ws_size,
                              hipStream_t stream)
{
    const int*   item_seq  = (const int*)  d_in[0];
    // d_in[1] click_sequence: unused by the reference
    const int*   seq_len   = (const int*)  d_in[2];
    const int*   tgt_item  = (const int*)  d_in[3];
    const float* ctx_feat  = (const float*)d_in[4];
    const float* emb       = (const float*)d_in[5];
    const float* aw1 = (const float*)d_in[6];
    const float* ab1 = (const float*)d_in[7];
    const float* aw2 = (const float*)d_in[8];
    const float* ab2 = (const float*)d_in[9];
    const float* aw3 = (const float*)d_in[10];
    const float* ab3 = (const float*)d_in[11];
    const float* cw  = (const float*)d_in[12];
    const float* cb  = (const float*)d_in[13];
    const float* mw1 = (const float*)d_in[14];
    const float* mb1 = (const float*)d_in[15];
    const float* mw2 = (const float*)d_in[16];
    const float* mb2 = (const float*)d_in[17];
    const float* mw3 = (const float*)d_in[18];
    const float* mb3 = (const float*)d_in[19];
    float* out = (float*)d_out;
    short* ws  = (short*)d_ws;

    hipLaunchKernelGGL(din_prep_kernel, dim3(6259), dim3(256), 0, stream,
                       emb, aw1, aw2, mw1, mw2, ws);
    hipLaunchKernelGGL(din_qc_kernel, dim3(128), dim3(256), 0, stream,
                       tgt_item, ab1, ws);
    hipLaunchKernelGGL(din_att_kernel, dim3(8192), dim3(256), 0, stream,
                       item_seq, seq_len, ab2, aw3, ab3, ws);
    hipLaunchKernelGGL(din_pool_kernel, dim3(2048), dim3(256), 0, stream,
                       item_seq, seq_len, tgt_item, ctx_feat, cw, cb, ws);
    hipLaunchKernelGGL(din_mlp_kernel, dim3(128), dim3(256), 0, stream,
                       mb1, mb2, mw3, mb3, ws, out);
}